// Round 7
// baseline (8023.387 us; speedup 1.0000x reference)
//
#include <hip/hip_runtime.h>
#include <math.h>

#define B_ 8
#define L_ 2048
#define D_ 1024
#define ED_ 2048
#define NL_ 3
#define NC_ 2
#define SCH_ 128              // scan chunk length
#define NCH_ (L_ / SCH_)      // 16 chunks

typedef unsigned short u16;
typedef unsigned int u32;
typedef __attribute__((ext_vector_type(8))) short short8;
typedef __attribute__((ext_vector_type(4))) float f32x4;

#define LOG2E_ 1.44269504088896f

__device__ __forceinline__ u16 f2b(float f) {
    u32 u = __float_as_uint(f);
    u = (u + 0x7FFFu + ((u >> 16) & 1u)) >> 16;
    return (u16)u;
}
__device__ __forceinline__ float b2f(u16 h) {
    return __uint_as_float(((u32)h) << 16);
}
__device__ __forceinline__ float fexp2(float x) {
#if __has_builtin(__builtin_amdgcn_exp2f)
    return __builtin_amdgcn_exp2f(x);
#else
    return exp2f(x);
#endif
}
__device__ __forceinline__ void cp16(const void* g, void* l) {
    __builtin_amdgcn_global_load_lds((const __attribute__((address_space(1))) u32*)g,
                                     (__attribute__((address_space(3))) u32*)l,
                                     16, 0, 0);
}

// DPP 16-lane sum (all lanes of each 16-lane row end with the row-group sum).
template<int CTRL>
__device__ __forceinline__ float dpp_add(float v) {
    int m = __builtin_amdgcn_update_dpp(0, __float_as_int(v), CTRL, 0xf, 0xf, false);
    return v + __int_as_float(m);
}
__device__ __forceinline__ float reduce16(float v) {
    v = dpp_add<0xB1>(v);    // quad_perm [1,0,3,2]  (xor 1)
    v = dpp_add<0x4E>(v);    // quad_perm [2,3,0,1]  (xor 2)
    v = dpp_add<0x124>(v);   // row_ror:4
    v = dpp_add<0x128>(v);   // row_ror:8
    return v;
}

// ---------------------------------------------------------------------------
// fp32 -> bf16 cast (RNE)
// ---------------------------------------------------------------------------
__global__ __launch_bounds__(256)
void cast_bf16(const float* __restrict__ in, u16* __restrict__ out, int n)
{
    int i = blockIdx.x * 256 + threadIdx.x;
    if (i < n) out[i] = f2b(in[i]);
}

// ---------------------------------------------------------------------------
// strided cast: dtb[m, 0:64] = bf16(xdbl[m, 0:64]) with xdbl row stride 192
// ---------------------------------------------------------------------------
__global__ __launch_bounds__(256)
void cast_dt(const float* __restrict__ xdbl, u16* __restrict__ dtb)
{
    int idx = blockIdx.x * 256 + threadIdx.x;   // M*64 threads
    int m = idx >> 6, r = idx & 63;
    dtb[idx] = f2b(xdbl[(size_t)m * 192 + r]);
}

// ---------------------------------------------------------------------------
// bf16 MFMA GEMM: C[M,N] = A[M,K] * W[N,K]^T   (A, W bf16)
// EPI: 0 = fp32 store, 1 = bf16 store, 2 = softplus(acc + bias) fp32 store
// BM=128, BN in {128,64}, BK=32. 256 threads = 4 waves.
// ---------------------------------------------------------------------------
template<int BN, int EPI>
__global__ __launch_bounds__(256)
void gemm_mfma(const u16* __restrict__ A, int lda,
               const u16* __restrict__ W, const float* __restrict__ bias,
               void* __restrict__ Cout, int ldc, int Kd)
{
    constexpr int WX = (BN == 128) ? 2 : 1;
    constexpr int WY = 4 / WX;
    constexpr int MI = (128 / WY) / 16;
    constexpr int NI = (BN / WX) / 16;
    constexpr int BISS = BN * 64 / 4096;

    __shared__ u16 As[128 * 32];
    __shared__ u16 Bs[BN * 32];

    const int tid  = threadIdx.x;
    const int wave = tid >> 6;
    const int lane = tid & 63;
    const int wy = wave / WX, wx = wave % WX;
    const int by = blockIdx.y * 128;
    const int bx = blockIdx.x * BN;
    const int lr = lane & 15;
    const int lk = (lane >> 4) * 8;

    f32x4 acc[MI][NI];
#pragma unroll
    for (int i = 0; i < MI; i++)
#pragma unroll
        for (int j = 0; j < NI; j++) acc[i][j] = (f32x4){0.f, 0.f, 0.f, 0.f};

    const u16* Ag0 = A + (size_t)(by + (tid >> 2)) * lda + (tid & 3) * 8;
    const u16* Bg0 = W + (size_t)(bx + (tid >> 2)) * Kd + (tid & 3) * 8;
    u16* ldsA0 = &As[wave * 512];
    u16* ldsA1 = &As[2048 + wave * 512];
    u16* ldsB0 = &Bs[wave * 512];
    u16* ldsB1 = &Bs[2048 + wave * 512];

    for (int kt = 0; kt < Kd; kt += 32) {
        __syncthreads();
        cp16(Ag0 + kt, ldsA0);
        cp16(Ag0 + (size_t)64 * lda + kt, ldsA1);
        cp16(Bg0 + kt, ldsB0);
        if (BISS == 2) cp16(Bg0 + (size_t)64 * Kd + kt, ldsB1);
        __syncthreads();

        short8 af[MI], bf[NI];
#pragma unroll
        for (int mi = 0; mi < MI; mi++) {
            int m = wy * (MI * 16) + mi * 16 + lr;
            af[mi] = *(const short8*)&As[m * 32 + lk];
        }
#pragma unroll
        for (int ni = 0; ni < NI; ni++) {
            int n = wx * (NI * 16) + ni * 16 + lr;
            bf[ni] = *(const short8*)&Bs[n * 32 + lk];
        }
#pragma unroll
        for (int mi = 0; mi < MI; mi++)
#pragma unroll
            for (int ni = 0; ni < NI; ni++)
                acc[mi][ni] = __builtin_amdgcn_mfma_f32_16x16x32_bf16(
                    af[mi], bf[ni], acc[mi][ni], 0, 0, 0);
    }

#pragma unroll
    for (int mi = 0; mi < MI; mi++) {
#pragma unroll
        for (int ni = 0; ni < NI; ni++) {
            int col = bx + wx * (NI * 16) + ni * 16 + lr;
#pragma unroll
            for (int r = 0; r < 4; r++) {
                int row = by + wy * (MI * 16) + mi * 16 + (lane >> 4) * 4 + r;
                float v = acc[mi][ni][r];
                if (EPI == 2) {
                    v += bias[col];
                    v = (v > 20.f) ? v : log1pf(__expf(v));
                }
                if (EPI == 1)
                    ((u16*)Cout)[(size_t)row * ldc + col] = f2b(v);
                else
                    ((float*)Cout)[(size_t)row * ldc + col] = v;
            }
        }
    }
}

// ---------------------------------------------------------------------------
// Depthwise causal conv (K=4) + bias + SiLU. bf16 in (xz, stride 4096), bf16 out.
// ---------------------------------------------------------------------------
__global__ __launch_bounds__(256)
void conv_silu(const u16* __restrict__ xzb, const float* __restrict__ cw,
               const float* __restrict__ cb, u16* __restrict__ xpb)
{
    int idx = blockIdx.x * 256 + threadIdx.x;
    int e = idx & (ED_ - 1);
    int l = (idx >> 11) & (L_ - 1);
    int b = idx >> 22;
    const float w0 = cw[e * 4 + 0], w1 = cw[e * 4 + 1];
    const float w2 = cw[e * 4 + 2], w3 = cw[e * 4 + 3];
    const u16* base = xzb + (size_t)(b * L_) * 4096 + e;
    float x0 = (l >= 3) ? b2f(base[(size_t)(l - 3) * 4096]) : 0.f;
    float x1 = (l >= 2) ? b2f(base[(size_t)(l - 2) * 4096]) : 0.f;
    float x2 = (l >= 1) ? b2f(base[(size_t)(l - 1) * 4096]) : 0.f;
    float x3 = b2f(base[(size_t)l * 4096]);
    float v = cb[e] + w0 * x0 + w1 * x1 + w2 * x2 + w3 * x3;
    v = v / (1.f + __expf(-v));
    xpb[idx] = f2b(v);
}

// ---------------------------------------------------------------------------
// Chunked selective scan. A pre-scaled by log2e -> raw v_exp (exp2).
// pass1: per-chunk scan from h=0 -> hbuf (h_out), sumd. Grid (128, NCH-1, G).
// 2-deep register pipeline; last 16-step block peeled (no per-step guards).
// ---------------------------------------------------------------------------
__global__ __launch_bounds__(256)
void scan_pass1(const float* __restrict__ delta, const float* __restrict__ xdbl,
                const u16* __restrict__ xpb, const float* __restrict__ A_log,
                float* __restrict__ hbuf, float* __restrict__ sumd)
{
    const int tid = threadIdx.x;
    const int c = tid >> 4, j = tid & 15;
    const int b = blockIdx.z, ch = blockIdx.y;
    const int e = (blockIdx.x << 4) + c;
    const int l0 = ch * SCH_;

    float4 Al = *(const float4*)(A_log + e * 64 + 4 * j);
    const float A0 = -__expf(Al.x) * LOG2E_, A1 = -__expf(Al.y) * LOG2E_;
    const float A2 = -__expf(Al.z) * LOG2E_, A3 = -__expf(Al.w) * LOG2E_;

    float h0 = 0.f, h1 = 0.f, h2 = 0.f, h3 = 0.f, sd = 0.f;
    int rowED  = (b * L_ + l0) * ED_ + e;      // consume/prefetch index (delta,x)
    int row192 = (b * L_ + l0) * 192;          // prefetch index (B)

    float  dv[2]; float4 Bv[2]; float xv[2];
#pragma unroll
    for (int p = 0; p < 2; ++p) {
        dv[p] = delta[rowED + p * ED_];
        Bv[p] = *(const float4*)(xdbl + row192 + p * 192 + 64 + 4 * j);
        xv[p] = b2f(xpb[rowED + p * ED_]);
    }
    int rowEDp  = rowED + 2 * ED_;             // next prefetch row (s+2)
    int row192p = row192 + 2 * 192;

#define P1_STEP(PF)                                                         \
    {                                                                       \
        float  d = dv[t & 1]; float4 Bc = Bv[t & 1]; float x = xv[t & 1];   \
        if (PF) {                                                           \
            dv[t & 1] = delta[rowEDp];                                      \
            Bv[t & 1] = *(const float4*)(xdbl + row192p + 64 + 4 * j);      \
            xv[t & 1] = b2f(xpb[rowEDp]);                                   \
            rowEDp += ED_; row192p += 192;                                  \
        }                                                                   \
        float dx = d * x;                                                   \
        h0 = fexp2(d * A0) * h0 + dx * Bc.x;                                \
        h1 = fexp2(d * A1) * h1 + dx * Bc.y;                                \
        h2 = fexp2(d * A2) * h2 + dx * Bc.z;                                \
        h3 = fexp2(d * A3) * h3 + dx * Bc.w;                                \
        sd += d;                                                            \
    }

    for (int kk = 0; kk < SCH_ / 16 - 1; ++kk) {
#pragma unroll
        for (int t = 0; t < 16; ++t) P1_STEP(true)
    }
#pragma unroll
    for (int t = 0; t < 16; ++t) P1_STEP(t < 14)
#undef P1_STEP

    int slot = ((b * NCH_ + ch) * ED_ + e) * 64 + 4 * j;
    *(float4*)(hbuf + slot) = make_float4(h0, h1, h2, h3);
    if (j == 0) sumd[(b * NCH_ + ch) * ED_ + e] = sd;
}

// ---------------------------------------------------------------------------
// pass2: sequential combine; hbuf[c] rewritten with h_in for chunk c.
// ---------------------------------------------------------------------------
__global__ __launch_bounds__(256)
void scan_pass2(float* __restrict__ hbuf, const float* __restrict__ sumd,
                const float* __restrict__ A_log)
{
    int idx = blockIdx.x * 256 + threadIdx.x;
    int n = idx & 63;
    int e = (idx >> 6) & (ED_ - 1);
    int b = idx >> 17;
    float A = -__expf(A_log[e * 64 + n]) * LOG2E_;
    float h = 0.f;
#pragma unroll
    for (int c = 0; c < NCH_; ++c) {
        int slot = ((b * NCH_ + c) * ED_ + e) * 64 + n;
        float v = 0.f, sd = 0.f;
        if (c < NCH_ - 1) {
            v  = hbuf[slot];
            sd = sumd[(b * NCH_ + c) * ED_ + e];
        }
        hbuf[slot] = h;                   // h_in for chunk c
        if (c < NCH_ - 1) h = fexp2(A * sd) * h + v;
    }
}

// ---------------------------------------------------------------------------
// pass3: re-scan from h_in; C-dot + DPP reduce; y rotated into lane (s&15);
// z-load + SiLU + bf16 store batched once per 16 steps. y IN PLACE over xpb.
// 2-deep register pipeline; last 16-step block peeled. Grid (128, NCH, G).
// ---------------------------------------------------------------------------
__global__ __launch_bounds__(256)
void scan_pass3(const float* __restrict__ delta, const float* __restrict__ xdbl,
                const u16* __restrict__ xzb, u16* __restrict__ xpb,
                const float* __restrict__ A_log, const float* __restrict__ Dp,
                const float* __restrict__ hbuf)
{
    const int tid = threadIdx.x;
    const int c = tid >> 4, j = tid & 15;
    const int b = blockIdx.z, ch = blockIdx.y;
    const int e = (blockIdx.x << 4) + c;
    const int l0 = ch * SCH_;

    float4 Al = *(const float4*)(A_log + e * 64 + 4 * j);
    const float A0 = -__expf(Al.x) * LOG2E_, A1 = -__expf(Al.y) * LOG2E_;
    const float A2 = -__expf(Al.z) * LOG2E_, A3 = -__expf(Al.w) * LOG2E_;
    const float dpe = Dp[e];

    int slot = ((b * NCH_ + ch) * ED_ + e) * 64 + 4 * j;
    float4 hi = *(const float4*)(hbuf + slot);
    float h0 = hi.x, h1 = hi.y, h2 = hi.z, h3 = hi.w;

    int rowED  = (b * L_ + l0) * ED_ + e;
    int row192 = (b * L_ + l0) * 192;
    int yRow   = rowED + j * ED_;              // epilogue row for this lane
    int zRow   = (b * L_ + l0 + j) * 4096 + ED_ + e;

    float  dv[2]; float4 Bv[2], Cv[2]; float xv[2];
#pragma unroll
    for (int p = 0; p < 2; ++p) {
        dv[p] = delta[rowED + p * ED_];
        Bv[p] = *(const float4*)(xdbl + row192 + p * 192 + 64 + 4 * j);
        Cv[p] = *(const float4*)(xdbl + row192 + p * 192 + 128 + 4 * j);
        xv[p] = b2f(xpb[rowED + p * ED_]);
    }
    int rowEDp  = rowED + 2 * ED_;
    int row192p = row192 + 2 * 192;

    float yreg = 0.f;

#define P3_STEP(PF)                                                         \
    {                                                                       \
        float  d = dv[t & 1]; float4 Bc = Bv[t & 1], Cc = Cv[t & 1];        \
        float  x = xv[t & 1];                                               \
        if (PF) {                                                           \
            dv[t & 1] = delta[rowEDp];                                      \
            Bv[t & 1] = *(const float4*)(xdbl + row192p + 64 + 4 * j);      \
            Cv[t & 1] = *(const float4*)(xdbl + row192p + 128 + 4 * j);     \
            xv[t & 1] = b2f(xpb[rowEDp]);                                   \
            rowEDp += ED_; row192p += 192;                                  \
        }                                                                   \
        float dx = d * x;                                                   \
        h0 = fexp2(d * A0) * h0 + dx * Bc.x;                                \
        h1 = fexp2(d * A1) * h1 + dx * Bc.y;                                \
        h2 = fexp2(d * A2) * h2 + dx * Bc.z;                                \
        h3 = fexp2(d * A3) * h3 + dx * Bc.w;                                \
        float acc = h0 * Cc.x + h1 * Cc.y + h2 * Cc.z + h3 * Cc.w;          \
        acc = reduce16(acc);                                                \
        float yv = acc + x * dpe;                                           \
        if (j == t) yreg = yv;                                              \
    }

#define P3_EPI                                                              \
    {                                                                       \
        float z = b2f(xzb[zRow]);                                           \
        float sz = z / (1.f + __expf(-z));                                  \
        xpb[yRow] = f2b(yreg * sz);                                         \
        yRow += 16 * ED_; zRow += 16 * 4096;                                \
    }

    for (int kk = 0; kk < SCH_ / 16 - 1; ++kk) {
#pragma unroll
        for (int t = 0; t < 16; ++t) P3_STEP(true)
        P3_EPI
    }
#pragma unroll
    for (int t = 0; t < 16; ++t) P3_STEP(t < 14)
    P3_EPI
#undef P3_STEP
#undef P3_EPI
}

// ---------------------------------------------------------------------------
// x = rmsnorm(t, norm_w) + x ; also writes bf16 copy of new x.
// ---------------------------------------------------------------------------
__global__ __launch_bounds__(256)
void rmsnorm_res(const float* __restrict__ t, const float* __restrict__ nw,
                 float* __restrict__ x, u16* __restrict__ xb)
{
    const int row = blockIdx.x;
    const int tid = threadIdx.x;
    const float* tr = t + (size_t)row * D_;
    float* xr = x + (size_t)row * D_;
    u16* xbr = xb + (size_t)row * D_;
    float4 v = *(const float4*)(tr + tid * 4);
    float ss = v.x * v.x + v.y * v.y + v.z * v.z + v.w * v.w;
#pragma unroll
    for (int m = 1; m < 64; m <<= 1) ss += __shfl_xor(ss, m);
    __shared__ float red[4];
    if ((tid & 63) == 0) red[tid >> 6] = ss;
    __syncthreads();
    float tot = red[0] + red[1] + red[2] + red[3];
    float scale = rsqrtf(tot * (1.f / (float)D_) + 1e-5f);
    float4 w = *(const float4*)(nw + tid * 4);
    float4 xo = *(const float4*)(xr + tid * 4);
    xo.x += v.x * scale * w.x;
    xo.y += v.y * scale * w.y;
    xo.z += v.z * scale * w.z;
    xo.w += v.w * scale * w.w;
    *(float4*)(xr + tid * 4) = xo;
    ushort4 hb;
    hb.x = f2b(xo.x); hb.y = f2b(xo.y); hb.z = f2b(xo.z); hb.w = f2b(xo.w);
    *(ushort4*)(xbr + tid * 4) = hb;
}

// ---------------------------------------------------------------------------
__global__ __launch_bounds__(256)
void head_kernel(const float* __restrict__ x, const float* __restrict__ Wh,
                 const float* __restrict__ bh, float* __restrict__ out)
{
    const int b = blockIdx.x >> 1, c = blockIdx.x & 1;
    const int tid = threadIdx.x;
    const float* xr = x + (size_t)(b * L_ + (L_ - 1)) * D_;
    const float* wr = Wh + c * D_;
    float4 xv = *(const float4*)(xr + tid * 4);
    float4 wv = *(const float4*)(wr + tid * 4);
    float s = xv.x * wv.x + xv.y * wv.y + xv.z * wv.z + xv.w * wv.w;
#pragma unroll
    for (int m = 1; m < 64; m <<= 1) s += __shfl_xor(s, m);
    __shared__ float red[4];
    if ((tid & 63) == 0) red[tid >> 6] = s;
    __syncthreads();
    if (tid == 0) out[b * 2 + c] = red[0] + red[1] + red[2] + red[3] + bh[c];
}

// ---------------------------------------------------------------------------
extern "C" void kernel_launch(void* const* d_in, const int* in_sizes, int n_in,
                              void* d_out, int out_size, void* d_ws, size_t ws_size,
                              hipStream_t stream)
{
    const float* x_in   = (const float*)d_in[0];
    const float* W_in   = (const float*)d_in[1];
    const float* conv_w = (const float*)d_in[2];
    const float* conv_b = (const float*)d_in[3];
    const float* W_x    = (const float*)d_in[4];
    const float* W_dt   = (const float*)d_in[5];
    const float* b_dt   = (const float*)d_in[6];
    const float* A_log  = (const float*)d_in[7];
    const float* D_p    = (const float*)d_in[8];
    const float* W_out  = (const float*)d_in[9];
    const float* norm_w = (const float*)d_in[10];
    const float* W_head = (const float*)d_in[11];
    const float* b_head = (const float*)d_in[12];
    float* out = (float*)d_out;

    // -------- bf16 weight region (fixed, head of ws) --------
    const size_t nWi = (size_t)NL_ * 2 * ED_ * D_;
    const size_t nWx = (size_t)NL_ * 192 * ED_;
    const size_t nWo = (size_t)NL_ * D_ * ED_;
    const size_t nWd = (size_t)NL_ * ED_ * 64;
    u16* Wi_b = (u16*)d_ws;
    u16* Wx_b = Wi_b + nWi;
    u16* Wo_b = Wx_b + nWx;
    u16* Wd_b = Wo_b + nWo;
    size_t wbytes = ((nWi + nWx + nWo + nWd) * 2 + 255) & ~(size_t)255;
    char* gb = (char*)d_ws + wbytes;
    size_t usable = ws_size - wbytes;

    cast_bf16<<<(int)(nWi / 256), 256, 0, stream>>>(W_in, Wi_b, (int)nWi);
    cast_bf16<<<(int)(nWx / 256), 256, 0, stream>>>(W_x,  Wx_b, (int)nWx);
    cast_bf16<<<(int)(nWo / 256), 256, 0, stream>>>(W_out, Wo_b, (int)nWo);
    cast_bf16<<<(int)(nWd / 256), 256, 0, stream>>>(W_dt,  Wd_b, (int)nWd);

    // per-batch: activations + hbuf + sumd + dtb
    const size_t perB = (size_t)L_ * (D_ * 4 + 192 * 4 + ED_ * 4 + 4096 * 2 + ED_ * 2)
                      + (size_t)NCH_ * ED_ * 64 * 4 + (size_t)NCH_ * ED_ * 4
                      + (size_t)L_ * 64 * 2;
    int G = 8;
    while (G > 1 && (size_t)G * perB > usable) G >>= 1;
    const int M = G * L_;

    // group-local layout
    float* x_cur = (float*)gb;                       // M*1024 f32
    float* xdbl  = x_cur + (size_t)M * D_;           // M*192  f32
    float* delta = xdbl + (size_t)M * 192;           // M*2048 f32
    u16*   x_b   = (u16*)delta;                      // alias (head of delta)
    u16*   xz_b  = (u16*)(delta + (size_t)M * ED_);  // M*4096 bf16
    u16*   xps_b = xz_b + (size_t)M * 4096;          // M*2048 bf16 (x, then y)
    float* hbuf  = (float*)(xps_b + (size_t)M * ED_);// G*NCH*ED*64 f32
    float* sumd  = hbuf + (size_t)G * NCH_ * ED_ * 64; // G*NCH*ED f32
    u16*   dtb   = (u16*)(sumd + (size_t)G * NCH_ * ED_); // M*64 bf16
    float* out_t = (float*)xz_b;                     // alias (GEMM3 out)

    for (int g0 = 0; g0 < B_; g0 += G) {
        const float* xg = x_in + (size_t)g0 * L_ * D_;
        hipMemcpyAsync(x_cur, xg, (size_t)M * D_ * sizeof(float),
                       hipMemcpyDeviceToDevice, stream);
        cast_bf16<<<(M * D_) / 256, 256, 0, stream>>>(xg, x_b, M * D_);

        for (int i = 0; i < NL_; ++i) {
            // 1) xz = x @ W_in^T  (M x 4096 x 1024), bf16 out
            gemm_mfma<128, 1><<<dim3(4096 / 128, M / 128), 256, 0, stream>>>(
                x_b, D_, Wi_b + (size_t)i * 2 * ED_ * D_, nullptr, xz_b, 4096, D_);
            // 2) xps = silu(conv(xp) + cb), bf16
            conv_silu<<<(M * ED_) / 256, 256, 0, stream>>>(
                xz_b, conv_w + (size_t)i * ED_ * 4, conv_b + (size_t)i * ED_, xps_b);
            // 3) xdbl = xps @ W_x^T  (M x 192 x 2048), fp32 out
            gemm_mfma<64, 0><<<dim3(192 / 64, M / 128), 256, 0, stream>>>(
                xps_b, ED_, Wx_b + (size_t)i * 192 * ED_, nullptr, xdbl, 192, ED_);
            // 4) dtb = bf16(xdbl[:, :64]); delta = softplus(dtb @ W_dt^T + b_dt)
            cast_dt<<<(M * 64) / 256, 256, 0, stream>>>(xdbl, dtb);
            gemm_mfma<128, 2><<<dim3(ED_ / 128, M / 128), 256, 0, stream>>>(
                dtb, 64, Wd_b + (size_t)i * ED_ * 64, b_dt + (size_t)i * ED_,
                delta, ED_, 64);
            // 5) chunked scan
            scan_pass1<<<dim3(128, NCH_ - 1, G), 256, 0, stream>>>(
                delta, xdbl, xps_b, A_log + (size_t)i * ED_ * 64, hbuf, sumd);
            scan_pass2<<<G * 512, 256, 0, stream>>>(
                hbuf, sumd, A_log + (size_t)i * ED_ * 64);
            scan_pass3<<<dim3(128, NCH_, G), 256, 0, stream>>>(
                delta, xdbl, xz_b, xps_b,
                A_log + (size_t)i * ED_ * 64, D_p + (size_t)i * ED_, hbuf);
            // 6) out_t = y @ W_out^T  (M x 1024 x 2048), fp32 out
            gemm_mfma<128, 0><<<dim3(D_ / 128, M / 128), 256, 0, stream>>>(
                xps_b, ED_, Wo_b + (size_t)i * D_ * ED_, nullptr, out_t, D_, ED_);
            // 7) x = rmsnorm(out_t) + x  (+ bf16 copy)
            rmsnorm_res<<<M, 256, 0, stream>>>(out_t, norm_w + (size_t)i * D_,
                                               x_cur, x_b);
        }
        head_kernel<<<G * NC_, 256, 0, stream>>>(x_cur, W_head, b_head,
                                                 out + (size_t)g0 * NC_);
    }
}